// Round 12
// baseline (460.681 us; speedup 1.0000x reference)
//
#include <hip/hip_runtime.h>

typedef unsigned short ushort_t;
typedef __bf16 bf16x8 __attribute__((ext_vector_type(8)));
typedef float f32x4 __attribute__((ext_vector_type(4)));

__device__ __forceinline__ ushort_t f2bf(float f) {
    unsigned int u = __float_as_uint(f);
    unsigned int r = (u + 0x7fffu + ((u >> 16) & 1u)) >> 16;
    return (ushort_t)r;
}
__device__ __forceinline__ float bf2f(ushort_t u) {
    return __uint_as_float(((unsigned int)u) << 16);
}
__device__ __forceinline__ unsigned pack_bf16(float a, float b) {
    // RNE bit-trick pack, bit-identical to baseline f2bf path
    return (unsigned)f2bf(a) | ((unsigned)f2bf(b) << 16);
}
__device__ __forceinline__ float wredsum(float v) {
    for (int o = 32; o; o >>= 1) v += __shfl_xor(v, o, 64);
    return v;
}
__device__ __forceinline__ float logsig(float z) {
    return (z >= 0.f) ? -log1pf(expf(-z)) : (z - log1pf(expf(z)));
}
__device__ __forceinline__ void msmerge(float& m, float& s, float om, float os) {
    float M = fmaxf(m, om);
    s = s * __expf(m - M) + os * __expf(om - M);
    m = M;
}

// ---------------- weight prep: Wov = Wo @ Wv, bvo = Wo@bv + bo ----------------
__global__ void k_wov(const float* __restrict__ Wo, const float* __restrict__ Wv,
                      const float* __restrict__ bvv, const float* __restrict__ bo,
                      ushort_t* __restrict__ Wovb, float* __restrict__ bvo) {
    int o = blockIdx.x, k = threadIdx.x;
    float s = 0.f;
    for (int j = 0; j < 256; ++j) s += Wo[o * 256 + j] * Wv[j * 256 + k];
    Wovb[o * 256 + k] = f2bf(s);
    float pb = Wo[o * 256 + k] * bvv[k];
    pb = wredsum(pb);
    __shared__ float sh[4];
    if ((k & 63) == 0) sh[k >> 6] = pb;
    __syncthreads();
    if (k == 0) bvo[o] = sh[0] + sh[1] + sh[2] + sh[3] + bo[o];
}

__global__ void k_cast_flat(const float* __restrict__ src, ushort_t* __restrict__ dst, int n) {
    int i = blockIdx.x * 256 + threadIdx.x;
    if (i < n) dst[i] = f2bf(src[i]);
}

// x (R,256) fp32 -> cat (R,512) bf16 at cols [0,256)
__global__ void k_cast_x(const float* __restrict__ src, ushort_t* __restrict__ dst) {
    long i = (long)blockIdx.x * 256 + threadIdx.x;
    long r = i >> 8;
    int c = (int)(i & 255);
    dst[r * 512 + c] = f2bf(src[i]);
}

// ---------------- fused adj pass: raw-transpose bf16 + row/col LSE partials ----------------
__global__ void k_prep(const float* __restrict__ adj, ushort_t* __restrict__ At10,
                       float* __restrict__ rowm, float* __restrict__ rows_,
                       float* __restrict__ colm, float* __restrict__ cols_) {
    int b = blockIdx.z;
    int n0 = blockIdx.x * 64, m0 = blockIdx.y * 64;
    __shared__ ushort_t T[64][72];
    int t = threadIdx.x;
    int r16 = t >> 4, cq = t & 15;
    const float* base = adj + ((long)b * 2048 + m0) * 2048 + n0;
#pragma unroll
    for (int p = 0; p < 4; ++p) {
        int row = p * 16 + r16;
        float4 v = *(const float4*)(base + (long)row * 2048 + cq * 4);
        float m = v.x, s = 1.f;
        msmerge(m, s, v.y, 1.f);
        msmerge(m, s, v.z, 1.f);
        msmerge(m, s, v.w, 1.f);
        for (int o = 1; o < 16; o <<= 1) {
            float om = __shfl_xor(m, o, 64);
            float os = __shfl_xor(s, o, 64);
            msmerge(m, s, om, os);
        }
        if (cq == 0) {
            int idx = (b * 32 + blockIdx.x) * 2048 + m0 + row;
            rowm[idx] = m; rows_[idx] = s;
        }
        T[cq * 4 + 0][row] = f2bf(v.x);
        T[cq * 4 + 1][row] = f2bf(v.y);
        T[cq * 4 + 2][row] = f2bf(v.z);
        T[cq * 4 + 3][row] = f2bf(v.w);
    }
    __syncthreads();
#pragma unroll
    for (int p = 0; p < 4; ++p) {
        int rn = p * 16 + r16;
        float v0 = bf2f(T[rn][cq * 4 + 0]);
        float v1 = bf2f(T[rn][cq * 4 + 1]);
        float v2 = bf2f(T[rn][cq * 4 + 2]);
        float v3 = bf2f(T[rn][cq * 4 + 3]);
        uint2 o;
        o.x = (unsigned)T[rn][cq * 4 + 0] | ((unsigned)T[rn][cq * 4 + 1] << 16);
        o.y = (unsigned)T[rn][cq * 4 + 2] | ((unsigned)T[rn][cq * 4 + 3] << 16);
        *(uint2*)&At10[((long)b * 2048 + n0 + rn) * 2048 + m0 + cq * 4] = o;
        float m = v0, s = 1.f;
        msmerge(m, s, v1, 1.f);
        msmerge(m, s, v2, 1.f);
        msmerge(m, s, v3, 1.f);
        for (int o2 = 1; o2 < 16; o2 <<= 1) {
            float om = __shfl_xor(m, o2, 64);
            float os = __shfl_xor(s, o2, 64);
            msmerge(m, s, om, os);
        }
        if (cq == 0) {
            int idx = (b * 32 + blockIdx.y) * 2048 + n0 + rn;
            colm[idx] = m; cols_[idx] = s;
        }
    }
}

// combine nch chunk partials -> LSE per (b, n)
__global__ void k_statcomb(const float* __restrict__ pm, const float* __restrict__ ps,
                           int nch, float* __restrict__ out) {
    int idx = blockIdx.x * 256 + threadIdx.x;  // 8192
    int b = idx >> 11, n = idx & 2047;
    float mx = -3.4e38f;
    for (int c = 0; c < nch; ++c) mx = fmaxf(mx, pm[(b * nch + c) * 2048 + n]);
    float s = 0.f;
    for (int c = 0; c < nch; ++c) s += ps[(b * nch + c) * 2048 + n] * __expf(pm[(b * nch + c) * 2048 + n] - mx);
    out[idx] = mx + logf(s);
}

// ---------------- ubuf (8 slabs 2048x256) -> B2 MFMA-fragment-tiled, slab-swapped ----------------
// B2 slab (z^4), per (w,kt): 64x64 tile stored as [frag f=kk*4+ni][lane=q*16+lm][8]:
//   B2[(z^4)][w][kt][f][lane][j] = ubuf[z][kt*64 + kk*32 + q*8 + j][w*64 + ni*16 + lm]
// Consumer (gemm_madj wave w) then reads each fragment as a fully-coalesced 1KiB
// wave load (lane l at base + l*16B) instead of 16x 4KB-strided 64B segments.
__global__ void k_trf(const ushort_t* __restrict__ src, ushort_t* __restrict__ dst) {
    int z = blockIdx.z;           // source slab
    int w = blockIdx.x;           // d-block 0..3
    int kt = blockIdx.y;          // k-block 0..31
    const ushort_t* s = src + (long)z * 524288 + (long)(kt * 64) * 256 + w * 64;
    ushort_t* d = dst + (((long)(z ^ 4) * 4 + w) * 32 + (long)kt) * 4096;
    __shared__ ushort_t T[64][68];   // T[dcol][krow]
    int t = threadIdx.x;
    int ir = t >> 4, jc = t & 15;
#pragma unroll
    for (int p = 0; p < 4; ++p) {
        int row = p * 16 + ir;
        uint2 v = *(const uint2*)&s[(long)row * 256 + jc * 4];
        T[jc * 4 + 0][row] = (ushort_t)(v.x & 0xffff);
        T[jc * 4 + 1][row] = (ushort_t)(v.x >> 16);
        T[jc * 4 + 2][row] = (ushort_t)(v.y & 0xffff);
        T[jc * 4 + 3][row] = (ushort_t)(v.y >> 16);
    }
    __syncthreads();
    int lane = t & 63, fh = t >> 6;
    int q = lane >> 4, lm = lane & 15;
#pragma unroll
    for (int fi = 0; fi < 2; ++fi) {
        int f = fi * 4 + fh;             // 0..7
        int kk = f >> 2, ni = f & 3;
        const ushort_t* tr = &T[ni * 16 + lm][kk * 32 + q * 8];
        uint2 a = *(const uint2*)&tr[0];
        uint2 b2 = *(const uint2*)&tr[4];
        int4 o;
        o.x = (int)a.x; o.y = (int)a.y; o.z = (int)b2.x; o.w = (int)b2.y;
        *(int4*)&d[(f * 64 + lane) * 8] = o;
    }
}

// ---------------- gemm64: 64x64 tile, 4 waves 2x2 of 32x32 ----------------
template <class Epi>
__global__ __launch_bounds__(256, 4) void gemm64(const ushort_t* __restrict__ A, int lda,
                                                 const ushort_t* __restrict__ Bt, int ldb,
                                                 int K, Epi epi) {
    __shared__ ushort_t lA[8 * 66 * 8];
    __shared__ ushort_t lB[8 * 66 * 8];
    const int m0 = blockIdx.x * 64, n0 = blockIdx.y * 64;
    const int t = threadIdx.x;
    const int lane = t & 63, wave = t >> 6;
    const int wm = (wave & 1) * 32, wn = (wave >> 1) * 32;
    const int q = lane >> 4, lm = lane & 15;
    const int r0 = t >> 3, kc = t & 7;
    const int r1 = 32 + r0;
    const int4* pa0 = (const int4*)(A + (long)(m0 + r0) * lda + kc * 8);
    const int4* pa1 = (const int4*)(A + (long)(m0 + r1) * lda + kc * 8);
    const int4* pb0 = (const int4*)(Bt + (long)(n0 + r0) * ldb + kc * 8);
    const int4* pb1 = (const int4*)(Bt + (long)(n0 + r1) * ldb + kc * 8);
    f32x4 zero = {0.f, 0.f, 0.f, 0.f};
    f32x4 acc[2][2];
    acc[0][0] = zero; acc[0][1] = zero; acc[1][0] = zero; acc[1][1] = zero;
    int4 ra0 = pa0[0], ra1 = pa1[0], rb0 = pb0[0], rb1 = pb1[0];
    const int nkt = K >> 6;
    for (int kt = 0; kt < nkt; ++kt) {
        __syncthreads();
        *(int4*)&lA[(kc * 66 + r0) * 8] = ra0;
        *(int4*)&lA[(kc * 66 + r1) * 8] = ra1;
        *(int4*)&lB[(kc * 66 + r0) * 8] = rb0;
        *(int4*)&lB[(kc * 66 + r1) * 8] = rb1;
        __syncthreads();
        if (kt + 1 < nkt) {
            ra0 = pa0[(kt + 1) * 8]; ra1 = pa1[(kt + 1) * 8];
            rb0 = pb0[(kt + 1) * 8]; rb1 = pb1[(kt + 1) * 8];
        }
#pragma unroll
        for (int kk = 0; kk < 2; ++kk) {
            bf16x8 af[2], bfr[2];
#pragma unroll
            for (int mi = 0; mi < 2; ++mi)
                af[mi] = *(const bf16x8*)&lA[((kk * 4 + q) * 66 + wm + mi * 16 + lm) * 8];
#pragma unroll
            for (int ni = 0; ni < 2; ++ni)
                bfr[ni] = *(const bf16x8*)&lB[((kk * 4 + q) * 66 + wn + ni * 16 + lm) * 8];
#pragma unroll
            for (int mi = 0; mi < 2; ++mi)
#pragma unroll
                for (int ni = 0; ni < 2; ++ni)
                    acc[mi][ni] = __builtin_amdgcn_mfma_f32_16x16x32_bf16(af[mi], bfr[ni], acc[mi][ni], 0, 0, 0);
        }
    }
#pragma unroll
    for (int mi = 0; mi < 2; ++mi)
#pragma unroll
        for (int ni = 0; ni < 2; ++ni)
#pragma unroll
            for (int r2 = 0; r2 < 4; ++r2) {
                int row = m0 + wm + mi * 16 + q * 4 + r2;
                int col = n0 + wn + ni * 16 + lm;
                epi(row, col, acc[mi][ni][r2]);
            }
}

struct GeU {
    ushort_t* dst; const float* bias;
    __device__ void operator()(int r, int c, float v) const {
        dst[(long)r * 256 + c] = f2bf(v + bias[c]);
    }
};
struct GeH {
    float* dst; const float* bias;
    __device__ void operator()(int r, int c, float v) const {
        dst[(long)r * 512 + c] = v + bias[c];
    }
};
struct GeD {
    ushort_t* dst; const float* bias; const float* x0; const float* x1;
    __device__ void operator()(int r, int c, float v) const {
        float rx = (r < 8192) ? x0[(long)r * 256 + c] : x1[(long)(r - 8192) * 256 + c];
        dst[(long)r * 256 + c] = f2bf(v + bias[c] + rx);
    }
};
// md epilogue: write mdb FRAGMENT-TILED for direct MFMA-register consumption by
// gemm_sim. addr = (((z*32+rb)*4+kt)*4096) + ((kk*4+ri)*64 + q*16 + lm)*8 + j
// where z=r>>11, rb=(r&2047)>>6, ri=(r>>4)&3, lm=r&15, kt=c>>6, kk=(c>>5)&1,
// q=(c>>3)&3, j=c&7. Same values (bit-identical), permuted storage.
struct GeMd {
    ushort_t* dst; const float* bias;
    __device__ void operator()(int r, int c, float v) const {
        int z = r >> 11;
        int rb = (r & 2047) >> 6;
        int ri = (r >> 4) & 3;
        int lmv = r & 15;
        int kt = c >> 6, kkv = (c >> 5) & 1, qv = (c >> 3) & 3, jv = c & 7;
        long addr = (((long)(z * 32 + rb)) * 4 + kt) * 4096
                  + (long)(((kkv * 4 + ri) * 64 + qv * 16 + lmv) * 8 + jv);
        dst[addr] = f2bf((v + bias[c]) * 0.25f);
    }
};

// ---------------- fused m-GEMM: softmax(adj) @ u -> cat bf16 ----------------
// v12: BM=64 (acc 4x4, 32 MFMA/wave/phase). Each 1KiB B fragment now feeds 4 MFMAs
//     (B L2 traffic halves to 256MB); barrier count unchanged (32) but per-phase
//     work doubles so prefetch distances in cycles double. Grid 256 blocks (1/CU,
//     no tail), __launch_bounds__(256,1) for VGPR headroom (v5 spill lesson).
//     XCD swizzle retained: x=bid&7, g=bid>>3: z=(x&3)+4*(g&1),
//     mtile=(g>>1)+16*(x>>2) -> each XCD touches exactly 2 ut slabs (L2-resident).
//     MFMA K-order and A/B bits unchanged -> bit-identical results.
__global__ __launch_bounds__(256, 1) void gemm_madj(
    const float* __restrict__ adj, const ushort_t* __restrict__ At10,
    const ushort_t* __restrict__ ut, const float* __restrict__ rlse,
    const float* __restrict__ clse, ushort_t* __restrict__ cat) {
    __shared__ ushort_t lA[2][8 * 67 * 8];
    __shared__ ushort_t stg[32 * 264];
    const int bid = blockIdx.x;
    const int xcd = bid & 7, g = bid >> 3;
    const int z = (xcd & 3) + 4 * (g & 1);
    const int m0 = ((g >> 1) + 16 * (xcd >> 2)) * 64;
    const int b = z & 3, side = z >> 2;
    const int t = threadIdx.x;
    const int lane = t & 63, wave = t >> 6;
    const int q = lane >> 4, lm = lane & 15;
    const float* rs = (side == 0 ? rlse : clse) + b * 2048 + m0;
    // B fragment base: fragment f of K-tile kt at pBW + kt*4096 + f*512 (elements)
    const ushort_t* pBW = ut + (((long)z * 4 + wave) * 32) * 4096 + lane * 8;
    // A staging addressing.
    // side 0 (fp32 adj): thread covers rows {ar, ar+16, ar+32, ar+48}, cols [ac4*4,+4)
    const int ar = t >> 4, ac4 = t & 15;
    const float* pafb = adj + ((long)(b * 2048 + m0 + ar)) * 2048 + ac4 * 4;
    float rlf[4];
#pragma unroll
    for (int i = 0; i < 4; ++i) rlf[i] = rs[i * 16 + ar];
    // side 1 (bf16 At10): thread covers rows {tr0, tr0+32}, granule tkc
    const int tr0 = t >> 3, tkc = t & 7;
    const int4* pat = (const int4*)(At10 + ((long)(b * 2048 + m0 + tr0)) * 2048 + tkc * 8);
    const float rlt0 = rs[tr0], rlt1 = rs[tr0 + 32];

    f32x4 zero = {0.f, 0.f, 0.f, 0.f};
    f32x4 acc[4][4];
#pragma unroll
    for (int mi = 0; mi < 4; ++mi)
#pragma unroll
        for (int ni = 0; ni < 4; ++ni) acc[mi][ni] = zero;

    float4 rfA[4], rfB[4];
    int4 rtA[2], rtB[2];
    bf16x8 bf0[8], bf1[8];

    auto loadA = [&](float4* rf, int4* rt, int kt) {
        if (side == 0) {
#pragma unroll
            for (int i = 0; i < 4; ++i)
                rf[i] = *(const float4*)(pafb + (long)i * 16 * 2048 + kt * 64);
        } else {
            rt[0] = pat[(long)kt * 8];
            rt[1] = pat[(long)32 * 2048 / 8 + (long)kt * 8];
        }
    };
    auto loadB = [&](bf16x8* dst, int kt) {
#pragma unroll
        for (int kk = 0; kk < 2; ++kk)
#pragma unroll
            for (int ni = 0; ni < 4; ++ni)
                dst[kk * 4 + ni] = *(const bf16x8*)&pBW[(long)kt * 4096 + (kk * 4 + ni) * 512];
    };
    auto writeA = [&](int po, const float4* rf, const int4* rt) {
        if (side == 0) {
#pragma unroll
            for (int i = 0; i < 4; ++i) {
                float4 v = rf[i];
                float rl = rlf[i];
                uint2 o;
                o.x = pack_bf16(__expf(v.x - rl), __expf(v.y - rl));
                o.y = pack_bf16(__expf(v.z - rl), __expf(v.w - rl));
                *(uint2*)&lA[po][((ac4 >> 1) * 67 + i * 16 + ar) * 8 + (ac4 & 1) * 4] = o;
            }
        } else {
#pragma unroll
            for (int jr = 0; jr < 2; ++jr) {
                const int4& w = rt[jr];
                float rl = jr ? rlt1 : rlt0;
                unsigned u0 = (unsigned)w.x, u1 = (unsigned)w.y;
                unsigned u2 = (unsigned)w.z, u3 = (unsigned)w.w;
                uint2 o0, o1;
                o0.x = pack_bf16(__expf(bf2f((ushort_t)(u0 & 0xffff)) - rl),
                                 __expf(bf2f((ushort_t)(u0 >> 16)) - rl));
                o0.y = pack_bf16(__expf(bf2f((ushort_t)(u1 & 0xffff)) - rl),
                                 __expf(bf2f((ushort_t)(u1 >> 16)) - rl));
                o1.x = pack_bf16(__expf(bf2f((ushort_t)(u2 & 0xffff)) - rl),
                                 __expf(bf2f((ushort_t)(u2 >> 16)) - rl));
                o1.y = pack_bf16(__expf(bf2f((ushort_t)(u3 & 0xffff)) - rl),
                                 __expf(bf2f((ushort_t)(u3 >> 16)) - rl));
                int row = tr0 + jr * 32;
                *(uint2*)&lA[po][(tkc * 67 + row) * 8] = o0;
                *(uint2*)&lA[po][(tkc * 67 + row) * 8 + 4] = o1;
            }
        }
    };
    auto compute = [&](int pi, const bf16x8* bfr) {
#pragma unroll
        for (int kk = 0; kk < 2; ++kk) {
            int gk = kk * 4 + q;
            bf16x8 af[4];
#pragma unroll
            for (int mi = 0; mi < 4; ++mi)
                af[mi] = *(const bf16x8*)&lA[pi][(gk * 67 + mi * 16 + lm) * 8];
#pragma unroll
            for (int mi = 0; mi < 4; ++mi)
#pragma unroll
                for (int ni = 0; ni < 4; ++ni)
                    acc[mi][ni] = __builtin_amdgcn_mfma_f32_16x16x32_bf16(
                        af[mi], bfr[kk * 4 + ni], acc[mi][ni], 0, 0, 0);
        }
    };
    // non-draining barrier: drain own LDS ops, leave global prefetches in flight
    auto phase_barrier = [&]() {
        asm volatile("s_waitcnt lgkmcnt(0)" ::: "memory");
        __builtin_amdgcn_s_barrier();
    };

    // prologue: A(0)->lA[0]; prefetch B(0),B(1) and A(1),A(2) into registers
    loadA(rfA, rtA, 0);
    loadB(bf0, 0);
    loadB(bf1, 1);
    writeA(0, rfA, rtA);
    loadA(rfB, rtB, 1);
    loadA(rfA, rtA, 2);
    phase_barrier();

#pragma unroll 1
    for (int kt2 = 0; kt2 < 16; ++kt2) {
        const int kt = kt2 * 2;
        // tile kt: lA[0], bf0
        compute(0, bf0);
        if (kt2 < 15) loadB(bf0, kt + 2);
        writeA(1, rfB, rtB);  // A(kt+1) -> lA[1]
        if (kt2 < 15) loadA(rfB, rtB, kt + 3);
        phase_barrier();
        // tile kt+1: lA[1], bf1
        compute(1, bf1);
        if (kt2 < 15) {
            loadB(bf1, kt + 3);
            writeA(0, rfA, rtA);  // A(kt+2) -> lA[0]
            if (kt2 < 14) loadA(rfA, rtA, kt + 4);
            phase_barrier();
        }
    }

    // epilogue: two passes of 32 rows staged in LDS, coalesced 16B stores
#pragma unroll 1
    for (int p = 0; p < 2; ++p) {
        __syncthreads();
#pragma unroll
        for (int mi = 0; mi < 2; ++mi)
#pragma unroll
            for (int ni = 0; ni < 4; ++ni)
#pragma unroll
                for (int r2 = 0; r2 < 4; ++r2) {
                    int row = mi * 16 + q * 4 + r2;
                    int col = wave * 64 + ni * 16 + lm;
                    stg[row * 264 + col] = f2bf(acc[p * 2 + mi][ni][r2]);
                }
        __syncthreads();
        {
            int row = t >> 3, ch = t & 7;
            long gaddr = ((long)(z * 2048 + m0 + p * 32 + row)) * 512 + 256 + ch * 32;
#pragma unroll
            for (int j = 0; j < 4; ++j)
                *(int4*)&cat[gaddr + j * 8] = *(const int4*)&stg[row * 264 + ch * 32 + j * 8];
        }
    }
}

// ---------------- sim GEMM: md0 @ md1^T (128x128 tile) + fused LSE partials ----------------
// grid (16 mtiles, 16 ntiles, 4 b)
// v8: mdb is fragment-tiled (GeMd), so BOTH A and B fragments load straight into
//     MFMA registers as fully-coalesced 1KiB wave transactions. No lA/lB LDS, zero
//     K-loop barriers (K=256 -> 4 frag-load+MFMA rounds). Epilogue re-laned:
//     4 contiguous 256B segments per store instruction.
__global__ __launch_bounds__(256, 2) void gemm_sim(
    const ushort_t* __restrict__ mdb, ushort_t* __restrict__ simb,
    float* __restrict__ rpm, float* __restrict__ rps,
    float* __restrict__ cpm, float* __restrict__ cps) {
    __shared__ ushort_t stg[128 * 136];
    __shared__ float rsm[128][2], rss[128][2], csm[128][2], css[128][2];
    const int b = blockIdx.z;
    const int m0 = blockIdx.x * 128, n0 = blockIdx.y * 128;
    const int t = threadIdx.x;
    const int lane = t & 63, wave = t >> 6;
    const int wm = (wave & 1) * 64, wn = (wave >> 1) * 64;
    const int q = lane >> 4, lm = lane & 15;
    const int rbA = blockIdx.x * 2 + (wave & 1);
    const int rbB = blockIdx.y * 2 + (wave >> 1);
    const ushort_t* pA = mdb + (((long)b * 32 + rbA) * 4) * 4096 + lane * 8;
    const ushort_t* pB = mdb + (((long)(4 + b) * 32 + rbB) * 4) * 4096 + lane * 8;
    f32x4 zero = {0.f, 0.f, 0.f, 0.f};
    f32x4 acc[4][4];
#pragma unroll
    for (int mi = 0; mi < 4; ++mi)
#pragma unroll
        for (int ni = 0; ni < 4; ++ni) acc[mi][ni] = zero;
    bf16x8 af[8], bfr[8];
#pragma unroll 1
    for (int kt = 0; kt < 4; ++kt) {
#pragma unroll
        for (int f = 0; f < 8; ++f) {
            af[f]  = *(const bf16x8*)&pA[(long)kt * 4096 + f * 512];
            bfr[f] = *(const bf16x8*)&pB[(long)kt * 4096 + f * 512];
        }
#pragma unroll
        for (int kk = 0; kk < 2; ++kk)
#pragma unroll
            for (int mi = 0; mi < 4; ++mi)
#pragma unroll
                for (int ni = 0; ni < 4; ++ni)
                    acc[mi][ni] = __builtin_amdgcn_mfma_f32_16x16x32_bf16(
                        af[kk * 4 + mi], bfr[kk * 4 + ni], acc[mi][ni], 0, 0, 0);
    }
    // row (max,sumexp) partials over this block's 128 cols
#pragma unroll
    for (int mi = 0; mi < 4; ++mi)
#pragma unroll
        for (int r2 = 0; r2 < 4; ++r2) {
            float mx = acc[mi][0][r2], sm = 1.f;
#pragma unroll
            for (int ni = 1; ni < 4; ++ni) msmerge(mx, sm, acc[mi][ni][r2], 1.f);
#pragma unroll
            for (int o = 1; o < 16; o <<= 1) {
                float om = __shfl_xor(mx, o, 64);
                float os = __shfl_xor(sm, o, 64);
                msmerge(mx, sm, om, os);
            }
            if (lm == 0) {
                int row = wm + mi * 16 + q * 4 + r2;
                rsm[row][wn >> 6] = mx; rss[row][wn >> 6] = sm;
            }
        }
    // col (max,sumexp) partials over this block's 128 rows
#pragma unroll
    for (int ni = 0; ni < 4; ++ni) {
        float mx = acc[0][ni][0], sm = 1.f;
#pragma unroll
        for (int mi = 0; mi < 4; ++mi)
#pragma unroll
            for (int r2 = 0; r2 < 4; ++r2) {
                if (mi == 0 && r2 == 0) continue;
                msmerge(mx, sm, acc[mi][ni][r2], 1.f);
            }
#pragma unroll
        for (int o = 16; o < 64; o <<= 1) {
            float om = __shfl_xor(mx, o, 64);
            float os = __shfl_xor(sm, o, 64);
            msmerge(mx, sm, om, os);
        }
        if (q == 0) {
            int col = wn + ni * 16 + lm;
            csm[col][wm >> 6] = mx; css[col][wm >> 6] = sm;
        }
    }
    // stage bf16 output
#pragma unroll
    for (int mi = 0; mi < 4; ++mi)
#pragma unroll
        for (int ni = 0; ni < 4; ++ni)
#pragma unroll
            for (int r2 = 0; r2 < 4; ++r2)
                stg[(wm + mi * 16 + q * 4 + r2) * 136 + wn + ni * 16 + lm] = f2bf(acc[mi][ni][r2]);
    __syncthreads();
    if (t < 128) {
        float m = rsm[t][0], s = rss[t][0];
        msmerge(m, s, rsm[t][1], rss[t][1]);
        int idx = (b * 16 + blockIdx.y) * 2048 + m0 + t;
        rpm[idx] = m; rps[idx] = s;
    } else {
        int c = t - 128;
        float m = csm[c][0], s = css[c][0];
        msmerge(m, s, csm[c][1], css[c][1]);
        int idx = (b * 16 + blockIdx.x) * 2048 + n0 + c;
        cpm[idx] = m; cps[idx] = s;
    }
    {
        int row8 = t >> 4, ch = t & 15;
#pragma unroll
        for (int j = 0; j < 8; ++j) {
            int row = j * 16 + row8;
            long g = (long)b * 4194304 + (long)(m0 + row) * 2048 + n0 + ch * 8;
            *(int4*)&simb[g] = *(const int4*)&stg[row * 136 + ch * 8];
        }
    }
}

// ---------------- LN + GELU (rows of 512) ----------------
__global__ void k_ln(const float* __restrict__ h, const float* __restrict__ lng,
                     const float* __restrict__ lnb, ushort_t* __restrict__ out) {
    int row = blockIdx.x;
    int t = threadIdx.x;
    const float* p = h + (long)row * 512;
    float a = p[t], c = p[t + 256];
    float s = wredsum(a + c);
    __shared__ float sh[4];
    if ((t & 63) == 0) sh[t >> 6] = s;
    __syncthreads();
    float mean = (sh[0] + sh[1] + sh[2] + sh[3]) * (1.f / 512.f);
    float da = a - mean, dc = c - mean;
    float s2 = wredsum(da * da + dc * dc);
    __shared__ float sh2[4];
    if ((t & 63) == 0) sh2[t >> 6] = s2;
    __syncthreads();
    float var = (sh2[0] + sh2[1] + sh2[2] + sh2[3]) * (1.f / 512.f);
    float inv = rsqrtf(var + 1e-5f);
    float x1 = da * inv * lng[t] + lnb[t];
    float x2 = dc * inv * lng[t + 256] + lnb[t + 256];
    float g1 = 0.5f * x1 * (1.f + erff(x1 * 0.70710678118654752f));
    float g2 = 0.5f * x2 * (1.f + erff(x2 * 0.70710678118654752f));
    out[(long)row * 512 + t] = f2bf(g1);
    out[(long)row * 512 + t + 256] = f2bf(g2);
}

// ---------------- z = d @ Wz + bz -> log_sigmoid(+-z); 16384 merged rows ----------------
__global__ void k_z(const ushort_t* __restrict__ dmat, const float* __restrict__ Wz,
                    const float* __restrict__ bzp, float* __restrict__ lszp,
                    float* __restrict__ lszn) {
    int row = blockIdx.x * 4 + (threadIdx.x >> 6);
    int l = threadIdx.x & 63;
    const ushort_t* p = dmat + (long)row * 256 + l * 4;
    float4 w = *(const float4*)(Wz + l * 4);
    float s = bf2f(p[0]) * w.x + bf2f(p[1]) * w.y + bf2f(p[2]) * w.z + bf2f(p[3]) * w.w;
    s = wredsum(s);
    if (l == 0) {
        float z = s + bzp[0];
        lszp[row] = logsig(z);
        lszn[row] = logsig(-z);
    }
}

// ---------------- fused: transform simb -> scores, row max/argmax, col-argmax partials ----------------
// grid 512: b = blk>>7, chunk of 16 rows = blk&127
__global__ void k_scores2(const ushort_t* __restrict__ simb, float* __restrict__ scores,
                          const float* __restrict__ rowLSE, const float* __restrict__ colLSE,
                          const float* __restrict__ lszp, const float* __restrict__ lszn,
                          float* __restrict__ rmax, int* __restrict__ ridx,
                          float* __restrict__ pcv, int* __restrict__ pci) {
    int blk = blockIdx.x;
    int b = blk >> 7, ch = blk & 127;
    int t = threadIdx.x;
    int lane = t & 63, wave = t >> 6;
    int n0 = t * 8;
    const float* cl = colLSE + b * 2048;
    const float* l1p = lszp + 8192 + b * 2048;
    float clv[8], l1v[8];
#pragma unroll
    for (int j = 0; j < 8; ++j) { clv[j] = cl[n0 + j]; l1v[j] = l1p[n0 + j]; }
    float cbv[8];
    int cbi[8];
#pragma unroll
    for (int j = 0; j < 8; ++j) { cbv[j] = -3.4e38f; cbi[j] = 0; }
    __shared__ float rv[16][4];
    __shared__ int ri[16][4];
    for (int r = 0; r < 16; ++r) {
        int m = ch * 16 + r;
        int gm = b * 2048 + m;
        float rl = rowLSE[gm], l0 = lszp[gm];
        float base = l0 - rl;
        int4 w = *(const int4*)&simb[(long)b * 4194304 + (long)m * 2048 + n0];
        unsigned u[4] = {(unsigned)w.x, (unsigned)w.y, (unsigned)w.z, (unsigned)w.w};
        float* dst = scores + (long)b * 4198401 + (long)m * 2049 + n0;
        float bv = -3.4e38f;
        int bi = 0;
#pragma unroll
        for (int i = 0; i < 4; ++i) {
#pragma unroll
            for (int h = 0; h < 2; ++h) {
                int j = i * 2 + h;
                float sv = bf2f((ushort_t)(h ? (u[i] >> 16) : (u[i] & 0xffff)));
                float tv = 2.f * sv + base;
                float v = tv - clv[j] + l1v[j];
                dst[j] = v;
                if (v > bv) { bv = v; bi = n0 + j; }
                if (tv > cbv[j]) { cbv[j] = tv; cbi[j] = m; }
            }
        }
        for (int o = 32; o; o >>= 1) {
            float ov = __shfl_xor(bv, o, 64);
            int oi = __shfl_xor(bi, o, 64);
            if (ov > bv || (ov == bv && oi < bi)) { bv = ov; bi = oi; }
        }
        if (lane == 0) { rv[r][wave] = bv; ri[r][wave] = bi; }
    }
    __syncthreads();
    if (t < 16) {
        float bv = rv[t][0];
        int bi = ri[t][0];
        for (int w2 = 1; w2 < 4; ++w2)
            if (rv[t][w2] > bv || (rv[t][w2] == bv && ri[t][w2] < bi)) { bv = rv[t][w2]; bi = ri[t][w2]; }
        int gm = b * 2048 + ch * 16 + t;
        rmax[gm] = bv;
        ridx[gm] = bi;
        scores[(long)b * 4198401 + (long)(ch * 16 + t) * 2049 + 2048] = lszn[gm];
    }
    long pidx = (long)(b * 128 + ch) * 2048 + n0;
#pragma unroll
    for (int j = 0; j < 8; ++j) { pcv[pidx + j] = cbv[j]; pci[pidx + j] = cbi[j]; }
}

// ---------------- combine col argmax chunks, write border row + corner ----------------
// v9: latency-bound fix. 8 lanes per (b,n) x 16 independent (pipelined) loads each,
//     shfl_xor tree reduce across the 8 chunk-groups, 256 blocks. Comparator is a
//     semilattice (lex max of (v,-i)) -> tree order == sequential order, bit-identical.
__global__ void k_colmaxB(const float* __restrict__ pcv, const int* __restrict__ pci,
                          const float* __restrict__ lszn, float* __restrict__ scores,
                          int* __restrict__ cidx) {
    int t = threadIdx.x;
    int wv = t >> 6, lane = t & 63;
    int nl = lane & 7, cg = lane >> 3;           // 8 n per wave, 8 chunk-groups
    int idx = blockIdx.x * 32 + wv * 8 + nl;     // global (b,n), 256 blocks x 32
    int b = idx >> 11, n = idx & 2047;
    float bv = -3.4e38f;
    int bi = 0;
    long base = ((long)b * 128 + cg * 16) * 2048 + n;
#pragma unroll
    for (int cc = 0; cc < 16; ++cc) {
        float v = pcv[base + (long)cc * 2048];
        int i = pci[base + (long)cc * 2048];
        if (v > bv || (v == bv && i < bi)) { bv = v; bi = i; }
    }
    for (int o = 8; o < 64; o <<= 1) {
        float ov = __shfl_xor(bv, o, 64);
        int oi = __shfl_xor(bi, o, 64);
        if (ov > bv || (ov == bv && oi < bi)) { bv = ov; bi = oi; }
    }
    if (cg == 0) {
        cidx[idx] = bi;
        scores[(long)b * 4198401 + 2048L * 2049 + n] = lszn[8192 + idx];
        if (n == 0) scores[(long)b * 4198401 + 2048L * 2049 + 2048] = 0.f;
    }
}

__global__ void k_match0(const int* __restrict__ ridx, const int* __restrict__ cidx,
                         const float* __restrict__ rmax, float* __restrict__ m0out,
                         float* __restrict__ ms0out, float* __restrict__ ms0ws,
                         int* __restrict__ v0ws) {
    int idx = blockIdx.x * 256 + threadIdx.x;
    int b = idx >> 11, m = idx & 2047;
    int j = ridx[idx];
    bool mutual = (cidx[b * 2048 + j] == m);
    float e = mutual ? expf(rmax[idx]) : 0.f;
    bool valid = mutual && (e > 0.1f);
    m0out[idx] = valid ? (float)j : -1.f;
    ms0out[idx] = e;
    ms0ws[idx] = e;
    v0ws[idx] = valid ? 1 : 0;
}

__global__ void k_match1(const int* __restrict__ cidx, const int* __restrict__ ridx,
                         const float* __restrict__ ms0ws, const int* __restrict__ v0ws,
                         float* __restrict__ m1out, float* __restrict__ ms1out) {
    int idx = blockIdx.x * 256 + threadIdx.x;
    int b = idx >> 11, n = idx & 2047;
    int j = cidx[idx];
    bool mutual = (ridx[b * 2048 + j] == n);
    float ms1 = mutual ? ms0ws[b * 2048 + j] : 0.f;
    bool valid = mutual && (v0ws[b * 2048 + j] != 0);
    m1out[idx] = valid ? (float)j : -1.f;
    ms1out[idx] = ms1;
}

extern "C" void kernel_launch(void* const* d_in, const int* in_sizes, int n_in,
                              void* d_out, int out_size, void* d_ws, size_t ws_size,
                              hipStream_t stream) {
    (void)in_sizes; (void)n_in; (void)out_size; (void)ws_size;
    const float* x0  = (const float*)d_in[0];
    const float* x1  = (const float*)d_in[1];
    const float* adj = (const float*)d_in[2];
    const float* Wv  = (const float*)d_in[3];
    const float* bv  = (const float*)d_in[4];
    const float* Wo  = (const float*)d_in[5];
    const float* bo  = (const float*)d_in[6];
    const float* Wf1 = (const float*)d_in[7];
    const float* bf1 = (const float*)d_in[8];
    const float* lng = (const float*)d_in[9];
    const float* lnb = (const float*)d_in[10];
    const float* Wf2 = (const float*)d_in[11];
    const float* bf2 = (const float*)d_in[12];
    const float* Wfp = (const float*)d_in[13];
    const float* bfp = (const float*)d_in[14];
    const float* Wz  = (const float*)d_in[15];
    const float* bz  = (const float*)d_in[16];

    float* out = (float*)d_out;
    float* scores  = out;
    float* out_m0  = out + 16793604;
    float* out_m1  = out_m0 + 8192;
    float* out_ms0 = out_m1 + 8192;
    float* out_ms1 = out_ms0 + 8192;

    char* base = (char*)d_ws;
    // [0, 33.5M): At10 raw bf16 (prep->madj), then hbuf fp32 (h-gemm->ln)
    ushort_t* At10 = (ushort_t*)base;
    float*    hbuf = (float*)base;
    // [33.5M, 67M): simb bf16 (sim-gemm -> scores2)
    ushort_t* simb = (ushort_t*)(base + 33554432);
    size_t off = 67108864;
    auto alloc = [&](size_t sz) { char* p = base + off; off += (sz + 255) & ~(size_t)255; return p; };
    ushort_t* cat  = (ushort_t*)alloc(16777216);   // 16384x512 bf16
    ushort_t* ubuf = (ushort_t*)alloc(8388608);    // 16384x256 bf16 ; later pcv (4MB)
    ushort_t* ut   = (ushort_t*)alloc(8388608);    // 8 slabs fragment-tiled ; later pci (4MB)
    ushort_t* gbuf = (ushort_t*)alloc(16777216);   // 16384x512 bf16
    ushort_t* dbuf = (ushort_t*)alloc(8388608);    // 16384x256 bf16
    ushort_t* mdb  = (ushort_t*)alloc(8388608);    // 16384x256 bf16, fragment-tiled
    ushort_t* Wovb = (ushort_t*)alloc(131072);
    ushort_t* Wf1b = (ushort_t*)alloc(524288);
    ushort_t* Wf2b = (ushort_t*)alloc(262144);
    ushort_t* Wfpb = (ushort_t*)alloc(131072);
    float* bvo     = (float*)alloc(1024);
    float* rowm    = (float*)alloc(1048576);
    float* rows_   = (float*)alloc(1048576);
    float* colm    = (float*)alloc(1048576);
    float* cols_   = (float*)alloc(1048576);
    float* rlse    = (float*)alloc(32768);
    float* clse    = (float*)alloc(32768);
    float* rpm     = (float*)alloc(524288);
    float* rps     = (float*)alloc(524288);
    float* cpm     = (float*)alloc(524288);
    float* cps     = (float*)alloc(524288);
    float* rowLSE  = (float*)alloc(32768);
    float* colLSE  = (float*)alloc(32768);
    float* rmax    = (float*)alloc(32768);
    int*   ridx    = (int*)alloc(32768);
    int*   cidx    = (int*)alloc(32768);
    float* lszp    = (float*)alloc(65536);
    float* lszn    = (float*)alloc(65536);
    float* ms0ws   = (float*)alloc(32768);
    int*   v0ws    = (int*)alloc(32768);
    float* pcv = (float*)ubuf;   // overlay: ubuf dead after k_trf
    int*   pci = (int*)ut;       // overlay: ut dead after gemm_madj

    // ---- weight prep + casts ----
    k_wov<<<256, 256, 0, stream>>>(Wo, Wv, bv, bo, Wovb, bvo);
    k_cast_flat<<<1024, 256, 0, stream>>>(Wf1, Wf1b, 262144);
    k_cast_flat<<<512, 256, 0, stream>>>(Wf2, Wf2b, 131072);
    k_cast_flat<<<256, 256, 0, stream>>>(Wfp, Wfpb, 65536);
    k_cast_x<<<8192, 256, 0, stream>>>(x0, cat);
    k_cast_x<<<8192, 256, 0, stream>>>(x1, cat + 8192L * 512);

    // ---- adjacency: raw transpose + fused LSE partials ----
    k_prep<<<dim3(32, 32, 4), 256, 0, stream>>>(adj, At10, rowm, rows_, colm, cols_);
    k_statcomb<<<32, 256, 0, stream>>>(rowm, rows_, 32, rlse);
    k_statcomb<<<32, 256, 0, stream>>>(colm, cols_, 32, clse);

    // ---- u = x @ Wov.T + bvo, then fragment-tiled transpose (slab-swapped) ----
    gemm64<<<dim3(256, 4), 256, 0, stream>>>(cat, 512, Wovb, 256, 256, GeU{ubuf, bvo});
    k_trf<<<dim3(4, 32, 8), 256, 0, stream>>>(ubuf, ut);

    // ---- fused m = softmax(adj) @ u -> cat[...,256:512] ----
    gemm_madj<<<dim3(256), 256, 0, stream>>>(adj, At10, ut, rlse, clse, cat);

    // ---- h = cat @ Wf1.T + bf1 ----
    gemm64<<<dim3(256, 8), 256, 0, stream>>>(cat, 512, Wf1b, 512, 512, GeH{hbuf, bf1});
    k_ln<<<16384, 256, 0, stream>>>(hbuf, lng, lnb, gbuf);

    // ---- d = x + g @ Wf2.T + bf2 ----
    gemm64<<<dim3(256, 4), 256, 0, stream>>>(gbuf, 512, Wf2b, 512, 512, GeD{dbuf, bf2, x0, x1});

    // ---- z / log_sigmoid ----
    k_z<<<4096, 256, 0, stream>>>(dbuf, Wz, bz, lszp, lszn);

    // ---- md = (d @ Wfp.T + bfp)/4 -> mdb fragment-tiled ----
    gemm64<<<dim3(256, 4), 256, 0, stream>>>(dbuf, 256, Wfpb, 256, 256, GeMd{mdb, bfp});

    // ---- sim = md0 @ md1^T -> simb bf16, with fused row/col LSE partials ----
    gemm_sim<<<dim3(16, 16, 4), 256, 0, stream>>>(mdb, simb, rpm, rps, cpm, cps);
    k_statcomb<<<32, 256, 0, stream>>>(rpm, rps, 16, rowLSE);
    k_statcomb<<<32, 256, 0, stream>>>(cpm, cps, 16, colLSE);

    // ---- transform + row argmax + col-argmax partials ----
    k_scores2<<<512, 256, 0, stream>>>(simb, scores, rowLSE, colLSE, lszp, lszn,
                                       rmax, ridx, pcv, pci);
    k_colmaxB<<<256, 256, 0, stream>>>(pcv, pci, lszn, scores, cidx);

    // ---- mutual matching ----
    k_match0<<<32, 256, 0, stream>>>(ridx, cidx, rmax, out_m0, out_ms0, ms0ws, v0ws);
    k_match1<<<32, 256, 0, stream>>>(cidx, ridx, ms0ws, v0ws, out_m1, out_ms1);
}

// Round 13
// 401.333 us; speedup vs baseline: 1.1479x; 1.1479x over previous
//
#include <hip/hip_runtime.h>

typedef unsigned short ushort_t;
typedef __bf16 bf16x8 __attribute__((ext_vector_type(8)));
typedef float f32x4 __attribute__((ext_vector_type(4)));

__device__ __forceinline__ ushort_t f2bf(float f) {
    unsigned int u = __float_as_uint(f);
    unsigned int r = (u + 0x7fffu + ((u >> 16) & 1u)) >> 16;
    return (ushort_t)r;
}
__device__ __forceinline__ float bf2f(ushort_t u) {
    return __uint_as_float(((unsigned int)u) << 16);
}
__device__ __forceinline__ unsigned pack_bf16(float a, float b) {
    // RNE bit-trick pack, bit-identical to baseline f2bf path
    return (unsigned)f2bf(a) | ((unsigned)f2bf(b) << 16);
}
__device__ __forceinline__ float wredsum(float v) {
    for (int o = 32; o; o >>= 1) v += __shfl_xor(v, o, 64);
    return v;
}
__device__ __forceinline__ float logsig(float z) {
    return (z >= 0.f) ? -log1pf(expf(-z)) : (z - log1pf(expf(z)));
}
__device__ __forceinline__ void msmerge(float& m, float& s, float om, float os) {
    float M = fmaxf(m, om);
    s = s * __expf(m - M) + os * __expf(om - M);
    m = M;
}

// ---------------- weight prep: Wov = Wo @ Wv, bvo = Wo@bv + bo ----------------
__global__ void k_wov(const float* __restrict__ Wo, const float* __restrict__ Wv,
                      const float* __restrict__ bvv, const float* __restrict__ bo,
                      ushort_t* __restrict__ Wovb, float* __restrict__ bvo) {
    int o = blockIdx.x, k = threadIdx.x;
    float s = 0.f;
    for (int j = 0; j < 256; ++j) s += Wo[o * 256 + j] * Wv[j * 256 + k];
    Wovb[o * 256 + k] = f2bf(s);
    float pb = Wo[o * 256 + k] * bvv[k];
    pb = wredsum(pb);
    __shared__ float sh[4];
    if ((k & 63) == 0) sh[k >> 6] = pb;
    __syncthreads();
    if (k == 0) bvo[o] = sh[0] + sh[1] + sh[2] + sh[3] + bo[o];
}

__global__ void k_cast_flat(const float* __restrict__ src, ushort_t* __restrict__ dst, int n) {
    int i = blockIdx.x * 256 + threadIdx.x;
    if (i < n) dst[i] = f2bf(src[i]);
}

// x (R,256) fp32 -> cat (R,512) bf16 at cols [0,256)
__global__ void k_cast_x(const float* __restrict__ src, ushort_t* __restrict__ dst) {
    long i = (long)blockIdx.x * 256 + threadIdx.x;
    long r = i >> 8;
    int c = (int)(i & 255);
    dst[r * 512 + c] = f2bf(src[i]);
}

// ---------------- fused adj pass: raw-transpose bf16 + row/col LSE partials ----------------
__global__ void k_prep(const float* __restrict__ adj, ushort_t* __restrict__ At10,
                       float* __restrict__ rowm, float* __restrict__ rows_,
                       float* __restrict__ colm, float* __restrict__ cols_) {
    int b = blockIdx.z;
    int n0 = blockIdx.x * 64, m0 = blockIdx.y * 64;
    __shared__ ushort_t T[64][72];
    int t = threadIdx.x;
    int r16 = t >> 4, cq = t & 15;
    const float* base = adj + ((long)b * 2048 + m0) * 2048 + n0;
#pragma unroll
    for (int p = 0; p < 4; ++p) {
        int row = p * 16 + r16;
        float4 v = *(const float4*)(base + (long)row * 2048 + cq * 4);
        float m = v.x, s = 1.f;
        msmerge(m, s, v.y, 1.f);
        msmerge(m, s, v.z, 1.f);
        msmerge(m, s, v.w, 1.f);
        for (int o = 1; o < 16; o <<= 1) {
            float om = __shfl_xor(m, o, 64);
            float os = __shfl_xor(s, o, 64);
            msmerge(m, s, om, os);
        }
        if (cq == 0) {
            int idx = (b * 32 + blockIdx.x) * 2048 + m0 + row;
            rowm[idx] = m; rows_[idx] = s;
        }
        T[cq * 4 + 0][row] = f2bf(v.x);
        T[cq * 4 + 1][row] = f2bf(v.y);
        T[cq * 4 + 2][row] = f2bf(v.z);
        T[cq * 4 + 3][row] = f2bf(v.w);
    }
    __syncthreads();
#pragma unroll
    for (int p = 0; p < 4; ++p) {
        int rn = p * 16 + r16;
        float v0 = bf2f(T[rn][cq * 4 + 0]);
        float v1 = bf2f(T[rn][cq * 4 + 1]);
        float v2 = bf2f(T[rn][cq * 4 + 2]);
        float v3 = bf2f(T[rn][cq * 4 + 3]);
        uint2 o;
        o.x = (unsigned)T[rn][cq * 4 + 0] | ((unsigned)T[rn][cq * 4 + 1] << 16);
        o.y = (unsigned)T[rn][cq * 4 + 2] | ((unsigned)T[rn][cq * 4 + 3] << 16);
        *(uint2*)&At10[((long)b * 2048 + n0 + rn) * 2048 + m0 + cq * 4] = o;
        float m = v0, s = 1.f;
        msmerge(m, s, v1, 1.f);
        msmerge(m, s, v2, 1.f);
        msmerge(m, s, v3, 1.f);
        for (int o2 = 1; o2 < 16; o2 <<= 1) {
            float om = __shfl_xor(m, o2, 64);
            float os = __shfl_xor(s, o2, 64);
            msmerge(m, s, om, os);
        }
        if (cq == 0) {
            int idx = (b * 32 + blockIdx.y) * 2048 + n0 + rn;
            colm[idx] = m; cols_[idx] = s;
        }
    }
}

// combine nch chunk partials -> LSE per (b, n)
// v13: latency fix (v9 recipe). Old: 32 blocks, 1 thread/(b,n), 2*nch strided
//     serial loads (~exposed L2/HBM latency at 12% CU use). New: 256 blocks,
//     8 lanes per (b,n) each covering nch/8 chunks; fmax tree (exact) then
//     per-lane partial sums vs the GLOBAL max + butterfly sum (fp32 sum
//     reassociates by ~1 ulp in the LSE; margin 0.125 vs 0.38 is ample).
__global__ void k_statcomb(const float* __restrict__ pm, const float* __restrict__ ps,
                           int nch, float* __restrict__ out) {
    int t = threadIdx.x;
    int wv = t >> 6, lane = t & 63;
    int nl = lane & 7, cg = lane >> 3;           // 8 (b,n) per wave, 8 chunk-groups
    int idx = blockIdx.x * 32 + wv * 8 + nl;     // 256 blocks x 32 = 8192
    int b = idx >> 11, n = idx & 2047;
    int per = nch >> 3;                          // 4 (nch=32) or 2 (nch=16)
    float mx = -3.4e38f;
    for (int j = 0; j < per; ++j) {
        int c = cg * per + j;
        mx = fmaxf(mx, pm[(long)(b * nch + c) * 2048 + n]);
    }
    for (int o = 8; o < 64; o <<= 1) mx = fmaxf(mx, __shfl_xor(mx, o, 64));
    float s = 0.f;
    for (int j = 0; j < per; ++j) {
        int c = cg * per + j;
        s += ps[(long)(b * nch + c) * 2048 + n] * __expf(pm[(long)(b * nch + c) * 2048 + n] - mx);
    }
    for (int o = 8; o < 64; o <<= 1) s += __shfl_xor(s, o, 64);
    if (cg == 0) out[idx] = mx + logf(s);
}

// ---------------- ubuf (8 slabs 2048x256) -> B2 MFMA-fragment-tiled, slab-swapped ----------------
// B2 slab (z^4), per (w,kt): 64x64 tile stored as [frag f=kk*4+ni][lane=q*16+lm][8]:
//   B2[(z^4)][w][kt][f][lane][j] = ubuf[z][kt*64 + kk*32 + q*8 + j][w*64 + ni*16 + lm]
// Consumer (gemm_madj wave w) then reads each fragment as a fully-coalesced 1KiB
// wave load (lane l at base + l*16B) instead of 16x 4KB-strided 64B segments.
__global__ void k_trf(const ushort_t* __restrict__ src, ushort_t* __restrict__ dst) {
    int z = blockIdx.z;           // source slab
    int w = blockIdx.x;           // d-block 0..3
    int kt = blockIdx.y;          // k-block 0..31
    const ushort_t* s = src + (long)z * 524288 + (long)(kt * 64) * 256 + w * 64;
    ushort_t* d = dst + (((long)(z ^ 4) * 4 + w) * 32 + (long)kt) * 4096;
    __shared__ ushort_t T[64][68];   // T[dcol][krow]
    int t = threadIdx.x;
    int ir = t >> 4, jc = t & 15;
#pragma unroll
    for (int p = 0; p < 4; ++p) {
        int row = p * 16 + ir;
        uint2 v = *(const uint2*)&s[(long)row * 256 + jc * 4];
        T[jc * 4 + 0][row] = (ushort_t)(v.x & 0xffff);
        T[jc * 4 + 1][row] = (ushort_t)(v.x >> 16);
        T[jc * 4 + 2][row] = (ushort_t)(v.y & 0xffff);
        T[jc * 4 + 3][row] = (ushort_t)(v.y >> 16);
    }
    __syncthreads();
    int lane = t & 63, fh = t >> 6;
    int q = lane >> 4, lm = lane & 15;
#pragma unroll
    for (int fi = 0; fi < 2; ++fi) {
        int f = fi * 4 + fh;             // 0..7
        int kk = f >> 2, ni = f & 3;
        const ushort_t* tr = &T[ni * 16 + lm][kk * 32 + q * 8];
        uint2 a = *(const uint2*)&tr[0];
        uint2 b2 = *(const uint2*)&tr[4];
        int4 o;
        o.x = (int)a.x; o.y = (int)a.y; o.z = (int)b2.x; o.w = (int)b2.y;
        *(int4*)&d[(f * 64 + lane) * 8] = o;
    }
}

// ---------------- gemm64: 64x64 tile, 4 waves 2x2 of 32x32 ----------------
template <class Epi>
__global__ __launch_bounds__(256, 4) void gemm64(const ushort_t* __restrict__ A, int lda,
                                                 const ushort_t* __restrict__ Bt, int ldb,
                                                 int K, Epi epi) {
    __shared__ ushort_t lA[8 * 66 * 8];
    __shared__ ushort_t lB[8 * 66 * 8];
    const int m0 = blockIdx.x * 64, n0 = blockIdx.y * 64;
    const int t = threadIdx.x;
    const int lane = t & 63, wave = t >> 6;
    const int wm = (wave & 1) * 32, wn = (wave >> 1) * 32;
    const int q = lane >> 4, lm = lane & 15;
    const int r0 = t >> 3, kc = t & 7;
    const int r1 = 32 + r0;
    const int4* pa0 = (const int4*)(A + (long)(m0 + r0) * lda + kc * 8);
    const int4* pa1 = (const int4*)(A + (long)(m0 + r1) * lda + kc * 8);
    const int4* pb0 = (const int4*)(Bt + (long)(n0 + r0) * ldb + kc * 8);
    const int4* pb1 = (const int4*)(Bt + (long)(n0 + r1) * ldb + kc * 8);
    f32x4 zero = {0.f, 0.f, 0.f, 0.f};
    f32x4 acc[2][2];
    acc[0][0] = zero; acc[0][1] = zero; acc[1][0] = zero; acc[1][1] = zero;
    int4 ra0 = pa0[0], ra1 = pa1[0], rb0 = pb0[0], rb1 = pb1[0];
    const int nkt = K >> 6;
    for (int kt = 0; kt < nkt; ++kt) {
        __syncthreads();
        *(int4*)&lA[(kc * 66 + r0) * 8] = ra0;
        *(int4*)&lA[(kc * 66 + r1) * 8] = ra1;
        *(int4*)&lB[(kc * 66 + r0) * 8] = rb0;
        *(int4*)&lB[(kc * 66 + r1) * 8] = rb1;
        __syncthreads();
        if (kt + 1 < nkt) {
            ra0 = pa0[(kt + 1) * 8]; ra1 = pa1[(kt + 1) * 8];
            rb0 = pb0[(kt + 1) * 8]; rb1 = pb1[(kt + 1) * 8];
        }
#pragma unroll
        for (int kk = 0; kk < 2; ++kk) {
            bf16x8 af[2], bfr[2];
#pragma unroll
            for (int mi = 0; mi < 2; ++mi)
                af[mi] = *(const bf16x8*)&lA[((kk * 4 + q) * 66 + wm + mi * 16 + lm) * 8];
#pragma unroll
            for (int ni = 0; ni < 2; ++ni)
                bfr[ni] = *(const bf16x8*)&lB[((kk * 4 + q) * 66 + wn + ni * 16 + lm) * 8];
#pragma unroll
            for (int mi = 0; mi < 2; ++mi)
#pragma unroll
                for (int ni = 0; ni < 2; ++ni)
                    acc[mi][ni] = __builtin_amdgcn_mfma_f32_16x16x32_bf16(af[mi], bfr[ni], acc[mi][ni], 0, 0, 0);
        }
    }
#pragma unroll
    for (int mi = 0; mi < 2; ++mi)
#pragma unroll
        for (int ni = 0; ni < 2; ++ni)
#pragma unroll
            for (int r2 = 0; r2 < 4; ++r2) {
                int row = m0 + wm + mi * 16 + q * 4 + r2;
                int col = n0 + wn + ni * 16 + lm;
                epi(row, col, acc[mi][ni][r2]);
            }
}

struct GeU {
    ushort_t* dst; const float* bias;
    __device__ void operator()(int r, int c, float v) const {
        dst[(long)r * 256 + c] = f2bf(v + bias[c]);
    }
};
struct GeH {
    float* dst; const float* bias;
    __device__ void operator()(int r, int c, float v) const {
        dst[(long)r * 512 + c] = v + bias[c];
    }
};
struct GeD {
    ushort_t* dst; const float* bias; const float* x0; const float* x1;
    __device__ void operator()(int r, int c, float v) const {
        float rx = (r < 8192) ? x0[(long)r * 256 + c] : x1[(long)(r - 8192) * 256 + c];
        dst[(long)r * 256 + c] = f2bf(v + bias[c] + rx);
    }
};
// md epilogue: write mdb FRAGMENT-TILED for direct MFMA-register consumption by
// gemm_sim. addr = (((z*32+rb)*4+kt)*4096) + ((kk*4+ri)*64 + q*16 + lm)*8 + j
// where z=r>>11, rb=(r&2047)>>6, ri=(r>>4)&3, lm=r&15, kt=c>>6, kk=(c>>5)&1,
// q=(c>>3)&3, j=c&7. Same values (bit-identical), permuted storage.
struct GeMd {
    ushort_t* dst; const float* bias;
    __device__ void operator()(int r, int c, float v) const {
        int z = r >> 11;
        int rb = (r & 2047) >> 6;
        int ri = (r >> 4) & 3;
        int lmv = r & 15;
        int kt = c >> 6, kkv = (c >> 5) & 1, qv = (c >> 3) & 3, jv = c & 7;
        long addr = (((long)(z * 32 + rb)) * 4 + kt) * 4096
                  + (long)(((kkv * 4 + ri) * 64 + qv * 16 + lmv) * 8 + jv);
        dst[addr] = f2bf((v + bias[c]) * 0.25f);
    }
};

// ---------------- fused m-GEMM: softmax(adj) @ u -> cat bf16 ----------------
// v11 (reverted from v12 regression): XCD-aware block swizzle for B-slab L2
//     residency. 1-D grid of 512; with round-robin dispatch XCD = bid%8.
//     x=bid&7, g=bid>>3: z=(x&3)+4*(g&1); mtile=(g>>1)+32*(x>>2) -> each XCD
//     touches exactly 2 ut slabs (2MB, L2-resident; FETCH 82->57MB confirmed).
//     K-step 64, fragment-tiled B in registers, 84 VGPR, non-draining barriers.
__global__ __launch_bounds__(256, 2) void gemm_madj(
    const float* __restrict__ adj, const ushort_t* __restrict__ At10,
    const ushort_t* __restrict__ ut, const float* __restrict__ rlse,
    const float* __restrict__ clse, ushort_t* __restrict__ cat) {
    __shared__ ushort_t lA[2][8 * 35 * 8];
    __shared__ ushort_t stg[32 * 264];
    const int bid = blockIdx.x;
    const int xcd = bid & 7, g = bid >> 3;
    const int z = (xcd & 3) + 4 * (g & 1);
    const int m0 = ((g >> 1) + 32 * (xcd >> 2)) * 32;
    const int b = z & 3, side = z >> 2;
    const int t = threadIdx.x;
    const int lane = t & 63, wave = t >> 6;
    const int q = lane >> 4, lm = lane & 15;
    const float* rs = (side == 0 ? rlse : clse) + b * 2048 + m0;
    // B fragment base: fragment f of K-tile kt at pBW + kt*4096 + f*512 (elements)
    const ushort_t* pBW = ut + (((long)z * 4 + wave) * 32) * 4096 + lane * 8;
    // A staging addressing (side 0: fp32 adj rows; side 1: bf16 At10 rows)
    const int ar = t >> 4, ac4 = t & 15;
    const float* paf0 = adj + ((long)(b * 2048 + m0 + ar)) * 2048 + ac4 * 4;
    const float* paf1 = paf0 + 16 * 2048;
    const float rlf0 = rs[ar], rlf1 = rs[16 + ar];
    const int tr0 = t >> 3, tkc = t & 7;
    const int4* pat = (const int4*)(At10 + ((long)(b * 2048 + m0 + tr0)) * 2048 + tkc * 8);
    const float rlt = rs[tr0];

    f32x4 zero = {0.f, 0.f, 0.f, 0.f};
    f32x4 acc[2][4];
#pragma unroll
    for (int mi = 0; mi < 2; ++mi)
#pragma unroll
        for (int ni = 0; ni < 4; ++ni) acc[mi][ni] = zero;

    float4 rfA[2], rfB[2];
    int4 rtA, rtB;
    bf16x8 bf0[8], bf1[8];

    auto loadA = [&](float4* rf, int4& rt, int kt) {
        if (side == 0) {
            rf[0] = *(const float4*)(paf0 + kt * 64);
            rf[1] = *(const float4*)(paf1 + kt * 64);
        } else {
            rt = pat[kt * 8];
        }
    };
    auto loadB = [&](bf16x8* dst, int kt) {
#pragma unroll
        for (int kk = 0; kk < 2; ++kk)
#pragma unroll
            for (int ni = 0; ni < 4; ++ni)
                dst[kk * 4 + ni] = *(const bf16x8*)&pBW[(long)kt * 4096 + (kk * 4 + ni) * 512];
    };
    auto writeA = [&](int po, const float4* rf, const int4& rt) {
        if (side == 0) {
#pragma unroll
            for (int i = 0; i < 2; ++i) {
                float4 v = rf[i];
                float rl = i ? rlf1 : rlf0;
                uint2 o;
                o.x = pack_bf16(__expf(v.x - rl), __expf(v.y - rl));
                o.y = pack_bf16(__expf(v.z - rl), __expf(v.w - rl));
                *(uint2*)&lA[po][((ac4 >> 1) * 35 + i * 16 + ar) * 8 + (ac4 & 1) * 4] = o;
            }
        } else {
            unsigned u0 = (unsigned)rt.x, u1 = (unsigned)rt.y;
            unsigned u2 = (unsigned)rt.z, u3 = (unsigned)rt.w;
            uint2 o0, o1;
            o0.x = pack_bf16(__expf(bf2f((ushort_t)(u0 & 0xffff)) - rlt),
                             __expf(bf2f((ushort_t)(u0 >> 16)) - rlt));
            o0.y = pack_bf16(__expf(bf2f((ushort_t)(u1 & 0xffff)) - rlt),
                             __expf(bf2f((ushort_t)(u1 >> 16)) - rlt));
            o1.x = pack_bf16(__expf(bf2f((ushort_t)(u2 & 0xffff)) - rlt),
                             __expf(bf2f((ushort_t)(u2 >> 16)) - rlt));
            o1.y = pack_bf16(__expf(bf2f((ushort_t)(u3 & 0xffff)) - rlt),
                             __expf(bf2f((ushort_t)(u3 >> 16)) - rlt));
            *(uint2*)&lA[po][(tkc * 35 + tr0) * 8] = o0;
            *(uint2*)&lA[po][(tkc * 35 + tr0) * 8 + 4] = o1;
        }
    };
    auto compute = [&](int pi, const bf16x8* bfr) {
#pragma unroll
        for (int kk = 0; kk < 2; ++kk) {
            bf16x8 af0 = *(const bf16x8*)&lA[pi][((kk * 4 + q) * 35 + lm) * 8];
            bf16x8 af1 = *(const bf16x8*)&lA[pi][((kk * 4 + q) * 35 + 16 + lm) * 8];
#pragma unroll
            for (int ni = 0; ni < 4; ++ni)
                acc[0][ni] = __builtin_amdgcn_mfma_f32_16x16x32_bf16(af0, bfr[kk * 4 + ni], acc[0][ni], 0, 0, 0);
#pragma unroll
            for (int ni = 0; ni < 4; ++ni)
                acc[1][ni] = __builtin_amdgcn_mfma_f32_16x16x32_bf16(af1, bfr[kk * 4 + ni], acc[1][ni], 0, 0, 0);
        }
    };
    // non-draining barrier: drain own LDS ops (producer->consumer visibility),
    // leave global prefetch loads in flight (counted vmcnt at use, 1.5 phases later)
    auto phase_barrier = [&]() {
        asm volatile("s_waitcnt lgkmcnt(0)" ::: "memory");
        __builtin_amdgcn_s_barrier();
    };

    // prologue: A(0)->lA[0]; prefetch B(0),B(1) and A(1),A(2) into registers
    loadA(rfA, rtA, 0);
    loadB(bf0, 0);
    loadB(bf1, 1);
    writeA(0, rfA, rtA);
    loadA(rfB, rtB, 1);
    loadA(rfA, rtA, 2);
    phase_barrier();

#pragma unroll 1
    for (int kt2 = 0; kt2 < 16; ++kt2) {
        const int kt = kt2 * 2;
        // tile kt: lA[0], bf0
        compute(0, bf0);
        if (kt2 < 15) loadB(bf0, kt + 2);
        writeA(1, rfB, rtB);  // A(kt+1) -> lA[1]
        if (kt2 < 15) loadA(rfB, rtB, kt + 3);
        phase_barrier();
        // tile kt+1: lA[1], bf1
        compute(1, bf1);
        if (kt2 < 15) {
            loadB(bf1, kt + 3);
            writeA(0, rfA, rtA);  // A(kt+2) -> lA[0]
            if (kt2 < 14) loadA(rfA, rtA, kt + 4);
            phase_barrier();
        }
    }

    // epilogue: stage 32x256 bf16 in LDS (stride 264), then coalesced 16B stores
    __syncthreads();
#pragma unroll
    for (int mi = 0; mi < 2; ++mi)
#pragma unroll
        for (int ni = 0; ni < 4; ++ni)
#pragma unroll
            for (int r2 = 0; r2 < 4; ++r2) {
                int row = mi * 16 + q * 4 + r2;
                int col = wave * 64 + ni * 16 + lm;
                stg[row * 264 + col] = f2bf(acc[mi][ni][r2]);
            }
    __syncthreads();
    {
        int row = t >> 3, ch = t & 7;
        long gaddr = ((long)(z * 2048 + m0 + row)) * 512 + 256 + ch * 32;
#pragma unroll
        for (int j = 0; j < 4; ++j)
            *(int4*)&cat[gaddr + j * 8] = *(const int4*)&stg[row * 264 + ch * 32 + j * 8];
    }
}

// ---------------- sim GEMM: md0 @ md1^T (128x128 tile) + fused LSE partials ----------------
// grid (16 mtiles, 16 ntiles, 4 b)
// v8: mdb is fragment-tiled (GeMd), so BOTH A and B fragments load straight into
//     MFMA registers as fully-coalesced 1KiB wave transactions. No lA/lB LDS, zero
//     K-loop barriers (K=256 -> 4 frag-load+MFMA rounds). Epilogue re-laned:
//     4 contiguous 256B segments per store instruction.
__global__ __launch_bounds__(256, 2) void gemm_sim(
    const ushort_t* __restrict__ mdb, ushort_t* __restrict__ simb,
    float* __restrict__ rpm, float* __restrict__ rps,
    float* __restrict__ cpm, float* __restrict__ cps) {
    __shared__ ushort_t stg[128 * 136];
    __shared__ float rsm[128][2], rss[128][2], csm[128][2], css[128][2];
    const int b = blockIdx.z;
    const int m0 = blockIdx.x * 128, n0 = blockIdx.y * 128;
    const int t = threadIdx.x;
    const int lane = t & 63, wave = t >> 6;
    const int wm = (wave & 1) * 64, wn = (wave >> 1) * 64;
    const int q = lane >> 4, lm = lane & 15;
    const int rbA = blockIdx.x * 2 + (wave & 1);
    const int rbB = blockIdx.y * 2 + (wave >> 1);
    const ushort_t* pA = mdb + (((long)b * 32 + rbA) * 4) * 4096 + lane * 8;
    const ushort_t* pB = mdb + (((long)(4 + b) * 32 + rbB) * 4) * 4096 + lane * 8;
    f32x4 zero = {0.f, 0.f, 0.f, 0.f};
    f32x4 acc[4][4];
#pragma unroll
    for (int mi = 0; mi < 4; ++mi)
#pragma unroll
        for (int ni = 0; ni < 4; ++ni) acc[mi][ni] = zero;
    bf16x8 af[8], bfr[8];
#pragma unroll 1
    for (int kt = 0; kt < 4; ++kt) {
#pragma unroll
        for (int f = 0; f < 8; ++f) {
            af[f]  = *(const bf16x8*)&pA[(long)kt * 4096 + f * 512];
            bfr[f] = *(const bf16x8*)&pB[(long)kt * 4096 + f * 512];
        }
#pragma unroll
        for (int kk = 0; kk < 2; ++kk)
#pragma unroll
            for (int mi = 0; mi < 4; ++mi)
#pragma unroll
                for (int ni = 0; ni < 4; ++ni)
                    acc[mi][ni] = __builtin_amdgcn_mfma_f32_16x16x32_bf16(
                        af[kk * 4 + mi], bfr[kk * 4 + ni], acc[mi][ni], 0, 0, 0);
    }
    // row (max,sumexp) partials over this block's 128 cols
#pragma unroll
    for (int mi = 0; mi < 4; ++mi)
#pragma unroll
        for (int r2 = 0; r2 < 4; ++r2) {
            float mx = acc[mi][0][r2], sm = 1.f;
#pragma unroll
            for (int ni = 1; ni < 4; ++ni) msmerge(mx, sm, acc[mi][ni][r2], 1.f);
#pragma unroll
            for (int o = 1; o < 16; o <<= 1) {
                float om = __shfl_xor(mx, o, 64);
                float os = __shfl_xor(sm, o, 64);
                msmerge(mx, sm, om, os);
            }
            if (lm == 0) {
                int row = wm + mi * 16 + q * 4 + r2;
                rsm[row][wn >> 6] = mx; rss[row][wn >> 6] = sm;
            }
        }
    // col (max,sumexp) partials over this block's 128 rows
#pragma unroll
    for (int ni = 0; ni < 4; ++ni) {
        float mx = acc[0][ni][0], sm = 1.f;
#pragma unroll
        for (int mi = 0; mi < 4; ++mi)
#pragma unroll
            for (int r2 = 0; r2 < 4; ++r2) {
                if (mi == 0 && r2 == 0) continue;
                msmerge(mx, sm, acc[mi][ni][r2], 1.f);
            }
#pragma unroll
        for (int o = 16; o < 64; o <<= 1) {
            float om = __shfl_xor(mx, o, 64);
            float os = __shfl_xor(sm, o, 64);
            msmerge(mx, sm, om, os);
        }
        if (q == 0) {
            int col = wn + ni * 16 + lm;
            csm[col][wm >> 6] = mx; css[col][wm >> 6] = sm;
        }
    }
    // stage bf16 output
#pragma unroll
    for (int mi = 0; mi < 4; ++mi)
#pragma unroll
        for (int ni = 0; ni < 4; ++ni)
#pragma unroll
            for (int r2 = 0; r2 < 4; ++r2)
                stg[(wm + mi * 16 + q * 4 + r2) * 136 + wn + ni * 16 + lm] = f2bf(acc[mi][ni][r2]);
    __syncthreads();
    if (t < 128) {
        float m = rsm[t][0], s = rss[t][0];
        msmerge(m, s, rsm[t][1], rss[t][1]);
        int idx = (b * 16 + blockIdx.y) * 2048 + m0 + t;
        rpm[idx] = m; rps[idx] = s;
    } else {
        int c = t - 128;
        float m = csm[c][0], s = css[c][0];
        msmerge(m, s, csm[c][1], css[c][1]);
        int idx = (b * 16 + blockIdx.x) * 2048 + n0 + c;
        cpm[idx] = m; cps[idx] = s;
    }
    {
        int row8 = t >> 4, ch = t & 15;
#pragma unroll
        for (int j = 0; j < 8; ++j) {
            int row = j * 16 + row8;
            long g = (long)b * 4194304 + (long)(m0 + row) * 2048 + n0 + ch * 8;
            *(int4*)&simb[g] = *(const int4*)&stg[row * 136 + ch * 8];
        }
    }
}

// ---------------- LN + GELU (rows of 512) ----------------
__global__ void k_ln(const float* __restrict__ h, const float* __restrict__ lng,
                     const float* __restrict__ lnb, ushort_t* __restrict__ out) {
    int row = blockIdx.x;
    int t = threadIdx.x;
    const float* p = h + (long)row * 512;
    float a = p[t], c = p[t + 256];
    float s = wredsum(a + c);
    __shared__ float sh[4];
    if ((t & 63) == 0) sh[t >> 6] = s;
    __syncthreads();
    float mean = (sh[0] + sh[1] + sh[2] + sh[3]) * (1.f / 512.f);
    float da = a - mean, dc = c - mean;
    float s2 = wredsum(da * da + dc * dc);
    __shared__ float sh2[4];
    if ((t & 63) == 0) sh2[t >> 6] = s2;
    __syncthreads();
    float var = (sh2[0] + sh2[1] + sh2[2] + sh2[3]) * (1.f / 512.f);
    float inv = rsqrtf(var + 1e-5f);
    float x1 = da * inv * lng[t] + lnb[t];
    float x2 = dc * inv * lng[t + 256] + lnb[t + 256];
    float g1 = 0.5f * x1 * (1.f + erff(x1 * 0.70710678118654752f));
    float g2 = 0.5f * x2 * (1.f + erff(x2 * 0.70710678118654752f));
    out[(long)row * 512 + t] = f2bf(g1);
    out[(long)row * 512 + t + 256] = f2bf(g2);
}

// ---------------- z = d @ Wz + bz -> log_sigmoid(+-z); 16384 merged rows ----------------
__global__ void k_z(const ushort_t* __restrict__ dmat, const float* __restrict__ Wz,
                    const float* __restrict__ bzp, float* __restrict__ lszp,
                    float* __restrict__ lszn) {
    int row = blockIdx.x * 4 + (threadIdx.x >> 6);
    int l = threadIdx.x & 63;
    const ushort_t* p = dmat + (long)row * 256 + l * 4;
    float4 w = *(const float4*)(Wz + l * 4);
    float s = bf2f(p[0]) * w.x + bf2f(p[1]) * w.y + bf2f(p[2]) * w.z + bf2f(p[3]) * w.w;
    s = wredsum(s);
    if (l == 0) {
        float z = s + bzp[0];
        lszp[row] = logsig(z);
        lszn[row] = logsig(-z);
    }
}

// ---------------- fused: transform simb -> scores, row max/argmax, col-argmax partials ----------------
// grid 512: b = blk>>7, chunk of 16 rows = blk&127
__global__ void k_scores2(const ushort_t* __restrict__ simb, float* __restrict__ scores,
                          const float* __restrict__ rowLSE, const float* __restrict__ colLSE,
                          const float* __restrict__ lszp, const float* __restrict__ lszn,
                          float* __restrict__ rmax, int* __restrict__ ridx,
                          float* __restrict__ pcv, int* __restrict__ pci) {
    int blk = blockIdx.x;
    int b = blk >> 7, ch = blk & 127;
    int t = threadIdx.x;
    int lane = t & 63, wave = t >> 6;
    int n0 = t * 8;
    const float* cl = colLSE + b * 2048;
    const float* l1p = lszp + 8192 + b * 2048;
    float clv[8], l1v[8];
#pragma unroll
    for (int j = 0; j < 8; ++j) { clv[j] = cl[n0 + j]; l1v[j] = l1p[n0 + j]; }
    float cbv[8];
    int cbi[8];
#pragma unroll
    for (int j = 0; j < 8; ++j) { cbv[j] = -3.4e38f; cbi[j] = 0; }
    __shared__ float rv[16][4];
    __shared__ int ri[16][4];
    for (int r = 0; r < 16; ++r) {
        int m = ch * 16 + r;
        int gm = b * 2048 + m;
        float rl = rowLSE[gm], l0 = lszp[gm];
        float base = l0 - rl;
        int4 w = *(const int4*)&simb[(long)b * 4194304 + (long)m * 2048 + n0];
        unsigned u[4] = {(unsigned)w.x, (unsigned)w.y, (unsigned)w.z, (unsigned)w.w};
        float* dst = scores + (long)b * 4198401 + (long)m * 2049 + n0;
        float bv = -3.4e38f;
        int bi = 0;
#pragma unroll
        for (int i = 0; i < 4; ++i) {
#pragma unroll
            for (int h = 0; h < 2; ++h) {
                int j = i * 2 + h;
                float sv = bf2f((ushort_t)(h ? (u[i] >> 16) : (u[i] & 0xffff)));
                float tv = 2.f * sv + base;
                float v = tv - clv[j] + l1v[j];
                dst[j] = v;
                if (v > bv) { bv = v; bi = n0 + j; }
                if (tv > cbv[j]) { cbv[j] = tv; cbi[j] = m; }
            }
        }
        for (int o = 32; o; o >>= 1) {
            float ov = __shfl_xor(bv, o, 64);
            int oi = __shfl_xor(bi, o, 64);
            if (ov > bv || (ov == bv && oi < bi)) { bv = ov; bi = oi; }
        }
        if (lane == 0) { rv[r][wave] = bv; ri[r][wave] = bi; }
    }
    __syncthreads();
    if (t < 16) {
        float bv = rv[t][0];
        int bi = ri[t][0];
        for (int w2 = 1; w2 < 4; ++w2)
            if (rv[t][w2] > bv || (rv[t][w2] == bv && ri[t][w2] < bi)) { bv = rv[t][w2]; bi = ri[t][w2]; }
        int gm = b * 2048 + ch * 16 + t;
        rmax[gm] = bv;
        ridx[gm] = bi;
        scores[(long)b * 4198401 + (long)(ch * 16 + t) * 2049 + 2048] = lszn[gm];
    }
    long pidx = (long)(b * 128 + ch) * 2048 + n0;
#pragma unroll
    for (int j = 0; j < 8; ++j) { pcv[pidx + j] = cbv[j]; pci[pidx + j] = cbi[j]; }
}

// ---------------- combine col argmax chunks, write border row + corner ----------------
// v9: latency-bound fix. 8 lanes per (b,n) x 16 independent (pipelined) loads each,
//     shfl_xor tree reduce across the 8 chunk-groups, 256 blocks. Comparator is a
//     semilattice (lex max of (v,-i)) -> tree order == sequential order, bit-identical.
__global__ void k_colmaxB(const float* __restrict__ pcv, const int* __restrict__ pci,
                          const float* __restrict__ lszn, float* __restrict__ scores,
                          int* __restrict__ cidx) {
    int t = threadIdx.x;
    int wv = t >> 6, lane = t & 63;
    int nl = lane & 7, cg = lane >> 3;           // 8 n per wave, 8 chunk-groups
    int idx = blockIdx.x * 32 + wv * 8 + nl;     // global (b,n), 256 blocks x 32
    int b = idx >> 11, n = idx & 2047;
    float bv = -3.4e38f;
    int bi = 0;
    long base = ((long)b * 128 + cg * 16) * 2048 + n;
#pragma unroll
    for (int cc = 0; cc < 16; ++cc) {
        float v = pcv[base + (long)cc * 2048];
        int i = pci[base + (long)cc * 2048];
        if (v > bv || (v == bv && i < bi)) { bv = v; bi = i; }
    }
    for (int o = 8; o < 64; o <<= 1) {
        float ov = __shfl_xor(bv, o, 64);
        int oi = __shfl_xor(bi, o, 64);
        if (ov > bv || (ov == bv && oi < bi)) { bv = ov; bi = oi; }
    }
    if (cg == 0) {
        cidx[idx] = bi;
        scores[(long)b * 4198401 + 2048L * 2049 + n] = lszn[8192 + idx];
        if (n == 0) scores[(long)b * 4198401 + 2048L * 2049 + 2048] = 0.f;
    }
}

__global__ void k_match0(const int* __restrict__ ridx, const int* __restrict__ cidx,
                         const float* __restrict__ rmax, float* __restrict__ m0out,
                         float* __restrict__ ms0out, float* __restrict__ ms0ws,
                         int* __restrict__ v0ws) {
    int idx = blockIdx.x * 256 + threadIdx.x;
    int b = idx >> 11, m = idx & 2047;
    int j = ridx[idx];
    bool mutual = (cidx[b * 2048 + j] == m);
    float e = mutual ? expf(rmax[idx]) : 0.f;
    bool valid = mutual && (e > 0.1f);
    m0out[idx] = valid ? (float)j : -1.f;
    ms0out[idx] = e;
    ms0ws[idx] = e;
    v0ws[idx] = valid ? 1 : 0;
}

__global__ void k_match1(const int* __restrict__ cidx, const int* __restrict__ ridx,
                         const float* __restrict__ ms0ws, const int* __restrict__ v0ws,
                         float* __restrict__ m1out, float* __restrict__ ms1out) {
    int idx = blockIdx.x * 256 + threadIdx.x;
    int b = idx >> 11, n = idx & 2047;
    int j = cidx[idx];
    bool mutual = (ridx[b * 2048 + j] == n);
    float ms1 = mutual ? ms0ws[b * 2048 + j] : 0.f;
    bool valid = mutual && (v0ws[b * 2048 + j] != 0);
    m1out[idx] = valid ? (float)j : -1.f;
    ms1out[idx] = ms1;
}

extern "C" void kernel_launch(void* const* d_in, const int* in_sizes, int n_in,
                              void* d_out, int out_size, void* d_ws, size_t ws_size,
                              hipStream_t stream) {
    (void)in_sizes; (void)n_in; (void)out_size; (void)ws_size;
    const float* x0  = (const float*)d_in[0];
    const float* x1  = (const float*)d_in[1];
    const float* adj = (const float*)d_in[2];
    const float* Wv  = (const float*)d_in[3];
    const float* bv  = (const float*)d_in[4];
    const float* Wo  = (const float*)d_in[5];
    const float* bo  = (const float*)d_in[6];
    const float* Wf1 = (const float*)d_in[7];
    const float* bf1 = (const float*)d_in[8];
    const float* lng = (const float*)d_in[9];
    const float* lnb = (const float*)d_in[10];
    const float* Wf2 = (const float*)d_in[11];
    const float* bf2 = (const float*)d_in[12];
    const float* Wfp = (const float*)d_in[13];
    const float* bfp = (const float*)d_in[14];
    const float* Wz  = (const float*)d_in[15];
    const float* bz  = (const float*)d_in[16];

    float* out = (float*)d_out;
    float* scores  = out;
    float* out_m0  = out + 16793604;
    float* out_m1  = out_m0 + 8192;
    float* out_ms0 = out_m1 + 8192;
    float* out_ms1 = out_ms0 + 8192;

    char* base = (char*)d_ws;
    // [0, 33.5M): At10 raw bf16 (prep->madj), then hbuf fp32 (h-gemm->ln)
    ushort_t* At10 = (ushort_t*)base;
    float*    hbuf = (float*)base;
    // [33.5M, 67M): simb bf16 (sim-gemm -> scores2)
    ushort_t* simb = (ushort_t*)(base + 33554432);
    size_t off = 67108864;
    auto alloc = [&](size_t sz) { char* p = base + off; off += (sz + 255) & ~(size_t)255; return p; };
    ushort_t* cat  = (ushort_t*)alloc(16777216);   // 16384x512 bf16
    ushort_t* ubuf = (ushort_t*)alloc(8388608);    // 16384x256 bf16 ; later pcv (4MB)
    ushort_t* ut   = (ushort_t*)alloc(8388608);    // 8 slabs fragment-tiled ; later pci (4MB)
    ushort_t* gbuf = (ushort_t*)alloc(16777216);   // 16384x512 bf16
    ushort_t* dbuf = (ushort_t*)alloc(8388608);    // 16384x256 bf16
    ushort_t* mdb  = (ushort_t*)alloc(8388608);    // 16384x256 bf16, fragment-tiled
    ushort_t* Wovb = (ushort_t*)alloc(131072);
    ushort_t* Wf1b = (ushort_t*)alloc(524288);
    ushort_t* Wf2b = (ushort_t*)alloc(262144);
    ushort_t* Wfpb = (ushort_t*)alloc(131072);
    float* bvo     = (float*)alloc(1024);
    float* rowm    = (float*)alloc(1048576);
    float* rows_   = (float*)alloc(1048576);
    float* colm    = (float*)alloc(1048576);
    float* cols_   = (float*)alloc(1048576);
    float* rlse    = (float*)alloc(32768);
    float* clse    = (float*)alloc(32768);
    float* rpm     = (float*)alloc(524288);
    float* rps     = (float*)alloc(524288);
    float* cpm     = (float*)alloc(524288);
    float* cps     = (float*)alloc(524288);
    float* rowLSE  = (float*)alloc(32768);
    float* colLSE  = (float*)alloc(32768);
    float* rmax    = (float*)alloc(32768);
    int*   ridx    = (int*)alloc(32768);
    int*   cidx    = (int*)alloc(32768);
    float* lszp    = (float*)alloc(65536);
    float* lszn    = (float*)alloc(65536);
    float* ms0ws   = (float*)alloc(32768);
    int*   v0ws    = (int*)alloc(32768);
    float* pcv = (float*)ubuf;   // overlay: ubuf dead after k_trf
    int*   pci = (int*)ut;       // overlay: ut dead after gemm_madj

    // ---- weight prep + casts ----
    k_wov<<<256, 256, 0, stream>>>(Wo, Wv, bv, bo, Wovb, bvo);
    k_cast_flat<<<1024, 256, 0, stream>>>(Wf1, Wf1b, 262144);
    k_cast_flat<<<512, 256, 0, stream>>>(Wf2, Wf2b, 131072);
    k_cast_flat<<<256, 256, 0, stream>>>(Wfp, Wfpb, 65536);
    k_cast_x<<<8192, 256, 0, stream>>>(x0, cat);
    k_cast_x<<<8192, 256, 0, stream>>>(x1, cat + 8192L * 512);

    // ---- adjacency: raw transpose + fused LSE partials ----
    k_prep<<<dim3(32, 32, 4), 256, 0, stream>>>(adj, At10, rowm, rows_, colm, cols_);
    k_statcomb<<<256, 256, 0, stream>>>(rowm, rows_, 32, rlse);
    k_statcomb<<<256, 256, 0, stream>>>(colm, cols_, 32, clse);

    // ---- u = x @ Wov.T + bvo, then fragment-tiled transpose (slab-swapped) ----
    gemm64<<<dim3(256, 4), 256, 0, stream>>>(cat, 512, Wovb, 256, 256, GeU{ubuf, bvo});
    k_trf<<<dim3(4, 32, 8), 256, 0, stream>>>(ubuf, ut);

    // ---- fused m = softmax(adj) @ u -> cat[...,256:512] ----
    gemm_madj<<<dim3(512), 256, 0, stream>>>(adj, At10, ut, rlse, clse, cat);

    // ---- h = cat @ Wf1.T + bf1 ----
    gemm64<<<dim3(256, 8), 256, 0, stream>>>(cat, 512, Wf1b, 512, 512, GeH{hbuf, bf1});
    k_ln<<<16384, 256, 0, stream>>>(hbuf, lng, lnb, gbuf);

    // ---- d = x + g @ Wf2.T + bf2 ----
    gemm64<<<dim3(256, 4), 256, 0, stream>>>(gbuf, 512, Wf2b, 512, 512, GeD{dbuf, bf2, x0, x1});

    // ---- z / log_sigmoid ----
    k_z<<<4096, 256, 0, stream>>>(dbuf, Wz, bz, lszp, lszn);

    // ---- md = (d @ Wfp.T + bfp)/4 -> mdb fragment-tiled ----
    gemm64<<<dim3(256, 4), 256, 0, stream>>>(dbuf, 256, Wfpb, 256, 256, GeMd{mdb, bfp});

    // ---- sim = md0 @ md1^T -> simb bf16, with fused row/col LSE partials ----
    gemm_sim<<<dim3(16, 16, 4), 256, 0, stream>>>(mdb, simb, rpm, rps, cpm, cps);
    k_statcomb<<<256, 256, 0, stream>>>(rpm, rps, 16, rowLSE);
    k_statcomb<<<256, 256, 0, stream>>>(cpm, cps, 16, colLSE);

    // ---- transform + row argmax + col-argmax partials ----
    k_scores2<<<512, 256, 0, stream>>>(simb, scores, rowLSE, colLSE, lszp, lszn,
                                       rmax, ridx, pcv, pci);
    k_colmaxB<<<256, 256, 0, stream>>>(pcv, pci, lszn, scores, cidx);

    // ---- mutual matching ----
    k_match0<<<32, 256, 0, stream>>>(ridx, cidx, rmax, out_m0, out_ms0, ms0ws, v0ws);
    k_match1<<<32, 256, 0, stream>>>(cidx, ridx, ms0ws, v0ws, out_m1, out_ms1);
}